// Round 1
// baseline (182.489 us; speedup 1.0000x reference)
//
#include <hip/hip_runtime.h>
#include <hip/hip_bf16.h>

// Problem constants
constexpr int Bb = 1024;   // batch
constexpr int Ii = 256;    // in features
constexpr int Oo = 256;    // out features
constexpr int Kk = 128;    // knots

__device__ __forceinline__ float bf16u_to_f(unsigned short u) {
    union { unsigned int ui; float f; } c;
    c.ui = ((unsigned int)u) << 16;
    return c.f;
}

// Kernel A: per-(b,i) scalar table, stored transposed [i][b] so the main
// kernel's inner b-loop reads contiguous float4s.
//   v = { frac, silu(tanh(x)), byte-offset of left row, byte-offset of right row }
__global__ void kprep(const float* __restrict__ x, float4* __restrict__ fls) {
    int tid = blockIdx.x * 256 + threadIdx.x;   // tid = i*Bb + b
    int i = tid >> 10;          // / 1024
    int b = tid & 1023;
    float xv = x[b * Ii + i];
    float p = tanhf(xv);
    float s = p / (1.f + __expf(-p));              // silu(p)
    float c = fminf(fmaxf(p, -1.f), 1.f);
    float scaled = (c + 1.f) * ((float)(Kk - 1) * 0.5f);   // (c - DMIN)/step
    int l = (int)floorf(scaled);
    l = min(max(l, 0), Kk - 1);
    int r = min(l + 1, Kk - 1);
    float f = scaled - (float)l;
    float4 v;
    v.x = f;
    v.y = s;
    v.z = __int_as_float(l * (Oo * 2));   // byte offset into bf16 [k][o] slab
    v.w = __int_as_float(r * (Oo * 2));
    fls[tid] = v;
}

// Kernel B: permute+scale Cs[o][i][k] -> Cp[i][k][o] in bf16 (rows over o are
// contiguous => the per-(b,i) gather becomes a coalesced row read).
// Piggybacked: out init to bias, and Wt[i][o] = W[o][i].
__global__ void kperm(const float* __restrict__ cs, const float* __restrict__ scale,
                      const float* __restrict__ wbase, const float* __restrict__ bias,
                      __hip_bfloat16* __restrict__ cp, float* __restrict__ wt,
                      float* __restrict__ out) {
    int o = threadIdx.x;
    int ik = blockIdx.x;            // i*Kk + k
    int i = ik >> 7, k = ik & (Kk - 1);
    float v = cs[(o * Ii + i) * Kk + k] * scale[o * Ii + i];
    cp[(size_t)ik * Oo + o] = __float2bfloat16(v);
    if (ik < Bb) out[ik * Oo + o] = bias[o];     // out[b][o] = bias[o]
    if (ik < Ii) wt[ik * Oo + o] = wbase[o * Ii + ik];
}

// Kernel C: main accumulation. 512 blocks = 64 b-tiles x 8 i-chunks.
// chunk = blk & 7 => all blocks of a chunk land on one XCD (round-robin
// dispatch), so that chunk's 2.1 MB Cp slice stays in its 4 MB L2.
// thread <-> o (256 threads), 16 batch accumulators per thread.
__global__ __launch_bounds__(256) void kmain(const float4* __restrict__ fls,
                                             const unsigned short* __restrict__ cp,
                                             const float* __restrict__ wt,
                                             float* __restrict__ out) {
    int o = threadIdx.x;
    int blk = blockIdx.x;
    int chunk = blk & 7;            // i-chunk, XCD-aligned
    int b0 = (blk >> 3) << 4;       // b-tile * 16
    int i0 = chunk * (Ii / 8);      // 32 i's per chunk

    float acc[16];
#pragma unroll
    for (int b = 0; b < 16; ++b) acc[b] = 0.f;

    for (int i = i0; i < i0 + (Ii / 8); ++i) {
        float w = wt[i * Oo + o];                        // reused across 16 b
        const char* cpi = (const char*)(cp + (size_t)i * Kk * Oo);
        const float4* fp = fls + i * Bb + b0;
#pragma unroll
        for (int b = 0; b < 16; ++b) {
            float4 v = fp[b];                            // wave-uniform broadcast
            float f = v.x, s = v.y;
            int lofs = __float_as_int(v.z);
            int rofs = __float_as_int(v.w);
            float cl = bf16u_to_f(*(const unsigned short*)(cpi + lofs + o * 2));
            float cr = bf16u_to_f(*(const unsigned short*)(cpi + rofs + o * 2));
            acc[b] = fmaf(s, w, acc[b]);                 // base term
            acc[b] = fmaf(1.f - f, cl, acc[b]);          // spline left
            acc[b] = fmaf(f, cr, acc[b]);                // spline right
        }
    }
#pragma unroll
    for (int b = 0; b < 16; ++b)
        atomicAdd(&out[(b0 + b) * Oo + o], acc[b]);      // 8 adds/element total
}

extern "C" void kernel_launch(void* const* d_in, const int* in_sizes, int n_in,
                              void* d_out, int out_size, void* d_ws, size_t ws_size,
                              hipStream_t stream) {
    const float* x     = (const float*)d_in[0];
    const float* wbase = (const float*)d_in[1];
    const float* coeff = (const float*)d_in[2];
    const float* scale = (const float*)d_in[3];
    const float* bias  = (const float*)d_in[4];
    float* out = (float*)d_out;

    char* ws = (char*)d_ws;
    float4* fls = (float4*)ws;                                       // 4 MB
    size_t off = (size_t)Bb * Ii * sizeof(float4);
    __hip_bfloat16* cp = (__hip_bfloat16*)(ws + off);                // 16 MB
    off += (size_t)Ii * Kk * Oo * sizeof(__hip_bfloat16);
    float* wt = (float*)(ws + off);                                  // 256 KB

    kprep<<<(Bb * Ii) / 256, 256, 0, stream>>>(x, fls);
    kperm<<<Ii * Kk, 256, 0, stream>>>(coeff, scale, wbase, bias, cp, wt, out);
    kmain<<<512, 256, 0, stream>>>(fls, (const unsigned short*)cp, wt, out);
}

// Round 2
// 150.917 us; speedup vs baseline: 1.2092x; 1.2092x over previous
//
#include <hip/hip_runtime.h>

// Problem constants
constexpr int Bb = 1024;   // batch
constexpr int Ii = 256;    // in features
constexpr int Oo = 256;    // out features
constexpr int Kk = 128;    // knots

typedef unsigned short u16;
typedef u16 ushort4v __attribute__((ext_vector_type(4)));

__device__ __forceinline__ float bf16u_to_f(u16 u) {
    union { unsigned int ui; float f; } c;
    c.ui = ((unsigned int)u) << 16;
    return c.f;
}
__device__ __forceinline__ u16 f_to_bf16(float f) {  // round-to-nearest-even
    union { float f; unsigned int u; } c; c.f = f;
    unsigned int r = c.u + 0x7fffu + ((c.u >> 16) & 1u);
    return (u16)(r >> 16);
}

// Kernel A: per-(b,i) scalar table stored [i][b] (contiguous b for the main
// kernel's broadcast reads). Also: out[b][o]=bias[o] init (needed for kmain's
// atomics) and Wt[i][o] = W[o][i].
//   v = { frac, silu(tanh(x)), byte-ofs of left row, byte-ofs of right row }
__global__ void kprep(const float* __restrict__ x, const float* __restrict__ wbase,
                      const float* __restrict__ bias, float4* __restrict__ fls,
                      float* __restrict__ wt, float* __restrict__ out) {
    int tid = blockIdx.x * 256 + threadIdx.x;   // tid = i*Bb + b
    int i = tid >> 10;
    int b = tid & 1023;
    float xv = x[b * Ii + i];
    // tanh via exp (fast, ~1e-7 rel err)
    float e2 = __expf(2.f * xv);
    float p = 1.f - 2.f / (e2 + 1.f);
    float s = p / (1.f + __expf(-p));              // silu(p)
    float c = fminf(fmaxf(p, -1.f), 1.f);
    float scaled = (c + 1.f) * ((float)(Kk - 1) * 0.5f);
    int l = (int)floorf(scaled);
    l = min(max(l, 0), Kk - 1);
    int r = min(l + 1, Kk - 1);
    float f = scaled - (float)l;
    float4 v;
    v.x = f;
    v.y = s;
    v.z = __int_as_float(l * (Oo * 2));   // byte offset into bf16 [k][o] slab
    v.w = __int_as_float(r * (Oo * 2));
    fls[tid] = v;

    out[tid] = bias[tid & (Oo - 1)];                         // out init
    if (tid < Ii * Oo) wt[tid] = wbase[(tid & 255) * Ii + (tid >> 8)];
}

// Kernel B: permute+scale Cs[o][i][k] -> Cp[i][k][o] bf16 via LDS transpose.
// grid = 256 i  x  2 o-halves. Reads coalesced along k, writes coalesced
// along o. LDS pitch 260 B => worst 2-way bank aliasing (free on gfx950).
__global__ __launch_bounds__(256) void kperm(const float* __restrict__ cs,
                                             const float* __restrict__ scale,
                                             u16* __restrict__ cp) {
    __shared__ u16 T[128 * 130];   // rows = o_local (128), pitch 130 ushorts
    int i  = blockIdx.x >> 1;
    int o0 = (blockIdx.x & 1) << 7;   // 0 or 128
    int t = threadIdx.x;

    // Phase 1: load Cs rows (float4 along k), scale, bf16 -> LDS
    {
        int c4 = t & 31;        // float4 index along k (k = c4*4)
        int rb = t >> 5;        // 0..7
        const float4* cs4 = (const float4*)cs;
#pragma unroll
        for (int p = 0; p < 16; ++p) {
            int r = p * 8 + rb;                 // o_local
            int o = o0 + r;
            float sc = scale[o * Ii + i];
            float4 val = cs4[(size_t)(o * Ii + i) * (Kk / 4) + c4];
            unsigned int lo = ((unsigned int)f_to_bf16(val.y) << 16) | f_to_bf16(val.x);
            unsigned int hi = ((unsigned int)f_to_bf16(val.w) << 16) | f_to_bf16(val.z);
            // apply scale before conversion
            lo = ((unsigned int)f_to_bf16(val.y * sc) << 16) | f_to_bf16(val.x * sc);
            hi = ((unsigned int)f_to_bf16(val.w * sc) << 16) | f_to_bf16(val.z * sc);
            *(unsigned int*)&T[r * 130 + c4 * 4]     = lo;
            *(unsigned int*)&T[r * 130 + c4 * 4 + 2] = hi;
        }
    }
    __syncthreads();
    // Phase 2: write Cp[i][k][o0..o0+128], lanes <-> o (coalesced stores)
    {
        int ol = t & 127;
        int kh = t >> 7;        // 0..1
        u16* dst = cp + ((size_t)i * Kk) * Oo + o0 + ol;
#pragma unroll
        for (int p = 0; p < 64; ++p) {
            int k = p * 2 + kh;
            dst[(size_t)k * Oo] = T[ol * 130 + k];
        }
    }
}

// Kernel C: main accumulation. 512 blocks = 64 b-tiles x 8 i-chunks.
// chunk = blk & 7 -> XCD-aligned (blk%8 round-robin), chunk slice of Cp is
// 2 MB <= 4 MB XCD L2. Thread owns o-quad (oq) x 4 b's: ushort4/float4 loads.
__global__ __launch_bounds__(256) void kmain(const float4* __restrict__ fls,
                                             const char* __restrict__ cpb,
                                             const float4* __restrict__ wt4,
                                             float* __restrict__ out) {
    int t = threadIdx.x;
    int oq = t & 63;            // o = oq*4 .. oq*4+3
    int bh = t >> 6;            // 0..3
    int blk = blockIdx.x;
    int chunk = blk & 7;
    int b0 = (blk >> 3) << 4;   // b-tile * 16
    int i0 = chunk * (Ii / 8);  // 32 i's per chunk

    float acc[4][4];
#pragma unroll
    for (int a = 0; a < 4; ++a)
#pragma unroll
        for (int j = 0; j < 4; ++j) acc[a][j] = 0.f;

#pragma unroll 2
    for (int i = i0; i < i0 + (Ii / 8); ++i) {
        float4 w = wt4[i * (Oo / 4) + oq];
        const char* cpi = cpb + (size_t)i * (Kk * Oo * 2);
        const float4* fp = fls + i * Bb + b0 + bh * 4;
#pragma unroll
        for (int bl = 0; bl < 4; ++bl) {
            float4 v = fp[bl];                       // wave-uniform broadcast
            int lofs = __float_as_int(v.z);
            int rofs = __float_as_int(v.w);
            ushort4v cl = *(const ushort4v*)(cpi + lofs + oq * 8);
            ushort4v cr = *(const ushort4v*)(cpi + rofs + oq * 8);
            float f = v.x, g = 1.f - v.x, s = v.y;
            acc[bl][0] = fmaf(s, w.x, acc[bl][0]);
            acc[bl][1] = fmaf(s, w.y, acc[bl][1]);
            acc[bl][2] = fmaf(s, w.z, acc[bl][2]);
            acc[bl][3] = fmaf(s, w.w, acc[bl][3]);
            acc[bl][0] = fmaf(g, bf16u_to_f(cl.x), acc[bl][0]);
            acc[bl][1] = fmaf(g, bf16u_to_f(cl.y), acc[bl][1]);
            acc[bl][2] = fmaf(g, bf16u_to_f(cl.z), acc[bl][2]);
            acc[bl][3] = fmaf(g, bf16u_to_f(cl.w), acc[bl][3]);
            acc[bl][0] = fmaf(f, bf16u_to_f(cr.x), acc[bl][0]);
            acc[bl][1] = fmaf(f, bf16u_to_f(cr.y), acc[bl][1]);
            acc[bl][2] = fmaf(f, bf16u_to_f(cr.z), acc[bl][2]);
            acc[bl][3] = fmaf(f, bf16u_to_f(cr.w), acc[bl][3]);
        }
    }
#pragma unroll
    for (int bl = 0; bl < 4; ++bl) {
        int b = b0 + bh * 4 + bl;
        float* op = out + b * Oo + oq * 4;
        atomicAdd(op + 0, acc[bl][0]);
        atomicAdd(op + 1, acc[bl][1]);
        atomicAdd(op + 2, acc[bl][2]);
        atomicAdd(op + 3, acc[bl][3]);
    }
}

extern "C" void kernel_launch(void* const* d_in, const int* in_sizes, int n_in,
                              void* d_out, int out_size, void* d_ws, size_t ws_size,
                              hipStream_t stream) {
    const float* x     = (const float*)d_in[0];
    const float* wbase = (const float*)d_in[1];
    const float* coeff = (const float*)d_in[2];
    const float* scale = (const float*)d_in[3];
    const float* bias  = (const float*)d_in[4];
    float* out = (float*)d_out;

    char* ws = (char*)d_ws;
    float4* fls = (float4*)ws;                                       // 4 MB
    size_t off = (size_t)Bb * Ii * sizeof(float4);
    u16* cp = (u16*)(ws + off);                                      // 16 MB
    off += (size_t)Ii * Kk * Oo * sizeof(u16);
    float* wt = (float*)(ws + off);                                  // 256 KB

    kprep<<<(Bb * Ii) / 256, 256, 0, stream>>>(x, wbase, bias, fls, wt, out);
    kperm<<<Ii * 2, 256, 0, stream>>>(coeff, scale, cp);
    kmain<<<512, 256, 0, stream>>>(fls, (const char*)cp, (const float4*)wt, out);
}

// Round 3
// 127.412 us; speedup vs baseline: 1.4323x; 1.1845x over previous
//
#include <hip/hip_runtime.h>

// Problem constants
constexpr int Bb = 1024;   // batch
constexpr int Ii = 256;    // in features
constexpr int Oo = 256;    // out features
constexpr int Kk = 128;    // knots

typedef unsigned short u16;
typedef u16 ushort4v __attribute__((ext_vector_type(4)));

__device__ __forceinline__ float bf16u_to_f(u16 u) {
    union { unsigned int ui; float f; } c;
    c.ui = ((unsigned int)u) << 16;
    return c.f;
}
__device__ __forceinline__ u16 f_to_bf16(float f) {  // round-to-nearest-even
    union { float f; unsigned int u; } c; c.f = f;
    unsigned int r = c.u + 0x7fffu + ((c.u >> 16) & 1u);
    return (u16)(r >> 16);
}

// Kernel A: per-(b,i) scalar table stored [b][i] (fully coalesced both here
// and in kmain's LDS staging). Also: out[b][o]=bias[o] init and Wt[i][o]=W[o][i].
//   v = { frac, silu(tanh(x)), byte-ofs of left row, byte-ofs of right row }
__global__ void kprep(const float* __restrict__ x, const float* __restrict__ wbase,
                      const float* __restrict__ bias, float4* __restrict__ fls,
                      float* __restrict__ wt, float* __restrict__ out) {
    int tid = blockIdx.x * 256 + threadIdx.x;   // tid = b*Ii + i
    float xv = x[tid];                          // coalesced
    float e2 = __expf(2.f * xv);
    float p = 1.f - 2.f / (e2 + 1.f);           // tanh
    float s = p / (1.f + __expf(-p));           // silu(p)
    float c = fminf(fmaxf(p, -1.f), 1.f);
    float scaled = (c + 1.f) * ((float)(Kk - 1) * 0.5f);
    int l = (int)floorf(scaled);
    l = min(max(l, 0), Kk - 1);
    int r = min(l + 1, Kk - 1);
    float f = scaled - (float)l;
    float4 v;
    v.x = f;
    v.y = s;
    v.z = __int_as_float(l * (Oo * 2));   // byte offset into bf16 [k][o] slab
    v.w = __int_as_float(r * (Oo * 2));
    fls[tid] = v;                               // [b][i], coalesced

    out[tid] = bias[tid & (Oo - 1)];            // out[b][o] = bias[o]
    if (tid < Ii * Oo) wt[tid] = wbase[(tid & 255) * Ii + (tid >> 8)];
}

// Kernel B: permute+scale Cs[o][i][k] -> Cp[i][k][o] bf16 via LDS transpose.
// grid = 256 i x 2 o-halves. Reads coalesced along k, writes coalesced
// along o. LDS pitch 130 u16 => worst 2-way bank aliasing (free on gfx950).
__global__ __launch_bounds__(256) void kperm(const float* __restrict__ cs,
                                             const float* __restrict__ scale,
                                             u16* __restrict__ cp) {
    __shared__ u16 T[128 * 130];   // rows = o_local (128), pitch 130 ushorts
    int i  = blockIdx.x >> 1;
    int o0 = (blockIdx.x & 1) << 7;   // 0 or 128
    int t = threadIdx.x;

    // Phase 1: load Cs rows (float4 along k), scale, bf16 -> LDS
    {
        int c4 = t & 31;        // float4 index along k (k = c4*4)
        int rb = t >> 5;        // 0..7
        const float4* cs4 = (const float4*)cs;
#pragma unroll
        for (int p = 0; p < 16; ++p) {
            int r = p * 8 + rb;                 // o_local
            int o = o0 + r;
            float sc = scale[o * Ii + i];
            float4 val = cs4[(size_t)(o * Ii + i) * (Kk / 4) + c4];
            unsigned int lo = ((unsigned int)f_to_bf16(val.y * sc) << 16) | f_to_bf16(val.x * sc);
            unsigned int hi = ((unsigned int)f_to_bf16(val.w * sc) << 16) | f_to_bf16(val.z * sc);
            *(unsigned int*)&T[r * 130 + c4 * 4]     = lo;
            *(unsigned int*)&T[r * 130 + c4 * 4 + 2] = hi;
        }
    }
    __syncthreads();
    // Phase 2: write Cp[i][k][o0..o0+128], lanes <-> o (coalesced stores)
    {
        int ol = t & 127;
        int kh = t >> 7;        // 0..1
        u16* dst = cp + ((size_t)i * Kk) * Oo + o0 + ol;
#pragma unroll
        for (int p = 0; p < 64; ++p) {
            int k = p * 2 + kh;
            dst[(size_t)k * Oo] = T[ol * 130 + k];
        }
    }
}

// Kernel C: main accumulation. 2048 blocks = 256 b-tiles (4 b) x 8 i-chunks
// (32 i). chunk = blk & 7 -> XCD-aligned (round-robin dispatch), chunk's Cp
// slice is 2 MB <= 4 MB XCD L2. Thread owns 1 b x 4 o, 32 i iterations.
// fls slice staged in LDS; 4x unroll keeps ~8 independent gathers in flight.
__global__ __launch_bounds__(256, 4) void kmain(const float4* __restrict__ fls,
                                                const char* __restrict__ cpb,
                                                const float4* __restrict__ wt4,
                                                float* __restrict__ out) {
    __shared__ float4 sf[128];           // [il][bl] : 32 i x 4 b
    int t = threadIdx.x;
    int blk = blockIdx.x;
    int chunk = blk & 7;
    int b0 = (blk >> 3) << 2;            // b-tile * 4
    int i0 = chunk << 5;                 // 32 i per chunk

    if (t < 128) {
        int il = t >> 2, bl = t & 3;     // sf[t] layout == [il][bl]
        // fls is [b][i]: for fixed bl, il-consecutive lanes read contiguous
        sf[t] = fls[(size_t)(b0 + bl) * Ii + i0 + il];
    }
    __syncthreads();

    int oq = t & 63;                     // o = oq*4 .. oq*4+3
    int bh = t >> 6;                     // 0..3 -> b = b0 + bh

    float a0 = 0.f, a1 = 0.f, a2 = 0.f, a3 = 0.f;
    const char* cbase = cpb + (size_t)i0 * (Kk * Oo * 2) + oq * 8;
#pragma unroll 4
    for (int il = 0; il < 32; ++il) {
        float4 v = sf[il * 4 + bh];                      // LDS broadcast
        float4 w = wt4[(i0 + il) * (Oo / 4) + oq];       // coalesced, L1-hot
        const char* ci = cbase + (size_t)il * (Kk * Oo * 2);
        ushort4v cl = *(const ushort4v*)(ci + __float_as_int(v.z));
        ushort4v cr = *(const ushort4v*)(ci + __float_as_int(v.w));
        float f = v.x, g = 1.f - v.x, s = v.y;
        a0 = fmaf(s, w.x, a0);
        a1 = fmaf(s, w.y, a1);
        a2 = fmaf(s, w.z, a2);
        a3 = fmaf(s, w.w, a3);
        a0 = fmaf(g, bf16u_to_f(cl.x), a0);
        a1 = fmaf(g, bf16u_to_f(cl.y), a1);
        a2 = fmaf(g, bf16u_to_f(cl.z), a2);
        a3 = fmaf(g, bf16u_to_f(cl.w), a3);
        a0 = fmaf(f, bf16u_to_f(cr.x), a0);
        a1 = fmaf(f, bf16u_to_f(cr.y), a1);
        a2 = fmaf(f, bf16u_to_f(cr.z), a2);
        a3 = fmaf(f, bf16u_to_f(cr.w), a3);
    }
    float* op = out + (size_t)(b0 + bh) * Oo + oq * 4;
    atomicAdd(op + 0, a0);
    atomicAdd(op + 1, a1);
    atomicAdd(op + 2, a2);
    atomicAdd(op + 3, a3);
}

extern "C" void kernel_launch(void* const* d_in, const int* in_sizes, int n_in,
                              void* d_out, int out_size, void* d_ws, size_t ws_size,
                              hipStream_t stream) {
    const float* x     = (const float*)d_in[0];
    const float* wbase = (const float*)d_in[1];
    const float* coeff = (const float*)d_in[2];
    const float* scale = (const float*)d_in[3];
    const float* bias  = (const float*)d_in[4];
    float* out = (float*)d_out;

    char* ws = (char*)d_ws;
    float4* fls = (float4*)ws;                                       // 4 MB
    size_t off = (size_t)Bb * Ii * sizeof(float4);
    u16* cp = (u16*)(ws + off);                                      // 16 MB
    off += (size_t)Ii * Kk * Oo * sizeof(u16);
    float* wt = (float*)(ws + off);                                  // 256 KB

    kprep<<<(Bb * Ii) / 256, 256, 0, stream>>>(x, wbase, bias, fls, wt, out);
    kperm<<<Ii * 2, 256, 0, stream>>>(coeff, scale, cp);
    kmain<<<2048, 256, 0, stream>>>(fls, (const char*)cp, (const float4*)wt, out);
}

// Round 4
// 116.759 us; speedup vs baseline: 1.5630x; 1.0912x over previous
//
#include <hip/hip_runtime.h>

// Problem constants
constexpr int Bb = 1024;   // batch
constexpr int Ii = 256;    // in features
constexpr int Oo = 256;    // out features
constexpr int Kk = 128;    // knots
constexpr int NCH = 8;     // i-chunks (XCD-aligned)

typedef unsigned short u16;
typedef u16 ushort4v __attribute__((ext_vector_type(4)));

__device__ __forceinline__ float bf16u_to_f(u16 u) {
    union { unsigned int ui; float f; } c;
    c.ui = ((unsigned int)u) << 16;
    return c.f;
}
__device__ __forceinline__ u16 f_to_bf16(float f) {  // round-to-nearest-even
    union { float f; unsigned int u; } c; c.f = f;
    unsigned int r = c.u + 0x7fffu + ((c.u >> 16) & 1u);
    return (u16)(r >> 16);
}

// Kernel A: per-(b,i) scalar table stored [b][i] (coalesced here and in
// kmain's LDS staging). Also Wt[i][o] = W[o][i].
//   v = { frac, silu(tanh(x)), byte-ofs of left row, byte-ofs of right row }
__global__ void kprep(const float* __restrict__ x, const float* __restrict__ wbase,
                      float4* __restrict__ fls, float* __restrict__ wt) {
    int tid = blockIdx.x * 256 + threadIdx.x;   // tid = b*Ii + i
    float xv = x[tid];                          // coalesced
    float e2 = __expf(2.f * xv);
    float p = 1.f - 2.f / (e2 + 1.f);           // tanh
    float s = p / (1.f + __expf(-p));           // silu(p)
    float c = fminf(fmaxf(p, -1.f), 1.f);
    float scaled = (c + 1.f) * ((float)(Kk - 1) * 0.5f);
    int l = (int)floorf(scaled);
    l = min(max(l, 0), Kk - 1);
    int r = min(l + 1, Kk - 1);
    float f = scaled - (float)l;
    float4 v;
    v.x = f;
    v.y = s;
    v.z = __int_as_float(l * (Oo * 2));   // byte offset into bf16 [k][o] slab
    v.w = __int_as_float(r * (Oo * 2));
    fls[tid] = v;                               // [b][i], coalesced

    if (tid < Ii * Oo) wt[tid] = wbase[(tid & 255) * Ii + (tid >> 8)];
}

// Kernel B: permute+scale Cs[o][i][k] -> Cp[i][k][o] bf16 via LDS transpose.
// grid = 256 i x 2 o-halves. Reads coalesced along k, writes coalesced
// along o. LDS pitch 130 u16 => worst 2-way bank aliasing (free on gfx950).
__global__ __launch_bounds__(256) void kperm(const float* __restrict__ cs,
                                             const float* __restrict__ scale,
                                             u16* __restrict__ cp) {
    __shared__ u16 T[128 * 130];   // rows = o_local (128), pitch 130 ushorts
    int i  = blockIdx.x >> 1;
    int o0 = (blockIdx.x & 1) << 7;   // 0 or 128
    int t = threadIdx.x;

    // Phase 1: load Cs rows (float4 along k), scale, bf16 -> LDS
    {
        int c4 = t & 31;        // float4 index along k (k = c4*4)
        int rb = t >> 5;        // 0..7
        const float4* cs4 = (const float4*)cs;
#pragma unroll
        for (int p = 0; p < 16; ++p) {
            int r = p * 8 + rb;                 // o_local
            int o = o0 + r;
            float sc = scale[o * Ii + i];
            float4 val = cs4[(size_t)(o * Ii + i) * (Kk / 4) + c4];
            unsigned int lo = ((unsigned int)f_to_bf16(val.y * sc) << 16) | f_to_bf16(val.x * sc);
            unsigned int hi = ((unsigned int)f_to_bf16(val.w * sc) << 16) | f_to_bf16(val.z * sc);
            *(unsigned int*)&T[r * 130 + c4 * 4]     = lo;
            *(unsigned int*)&T[r * 130 + c4 * 4 + 2] = hi;
        }
    }
    __syncthreads();
    // Phase 2: write Cp[i][k][o0..o0+128], lanes <-> o (coalesced stores)
    {
        int ol = t & 127;
        int kh = t >> 7;        // 0..1
        u16* dst = cp + ((size_t)i * Kk) * Oo + o0 + ol;
#pragma unroll
        for (int p = 0; p < 64; ++p) {
            int k = p * 2 + kh;
            dst[(size_t)k * Oo] = T[ol * 130 + k];
        }
    }
}

// Kernel C: main accumulation. 2048 blocks = 256 b-tiles (4 b) x 8 i-chunks
// (32 i). chunk = blk & 7 -> XCD-aligned (round-robin dispatch), chunk's Cp
// slice is 2 MB <= 4 MB XCD L2. Thread owns 1 b x 4 o, 32 i iterations.
// NO atomics: each block stores its partial tile to partial[chunk][b][o]
// (plain coalesced stores; unique writer per address). kreduce sums chunks.
__global__ __launch_bounds__(256, 4) void kmain(const float4* __restrict__ fls,
                                                const char* __restrict__ cpb,
                                                const float4* __restrict__ wt4,
                                                float4* __restrict__ part4) {
    __shared__ float4 sf[128];           // [il][bl] : 32 i x 4 b
    int t = threadIdx.x;
    int blk = blockIdx.x;
    int chunk = blk & (NCH - 1);
    int b0 = (blk >> 3) << 2;            // b-tile * 4
    int i0 = chunk << 5;                 // 32 i per chunk

    if (t < 128) {
        int il = t >> 2, bl = t & 3;     // sf[t] layout == [il][bl]
        sf[t] = fls[(size_t)(b0 + bl) * Ii + i0 + il];
    }
    __syncthreads();

    int oq = t & 63;                     // o = oq*4 .. oq*4+3
    int bh = t >> 6;                     // 0..3 -> b = b0 + bh

    float a0 = 0.f, a1 = 0.f, a2 = 0.f, a3 = 0.f;
    const char* cbase = cpb + (size_t)i0 * (Kk * Oo * 2) + oq * 8;
#pragma unroll 8
    for (int il = 0; il < 32; ++il) {
        float4 v = sf[il * 4 + bh];                      // LDS broadcast
        float4 w = wt4[(i0 + il) * (Oo / 4) + oq];       // coalesced, L1-hot
        const char* ci = cbase + (size_t)il * (Kk * Oo * 2);
        ushort4v cl = *(const ushort4v*)(ci + __float_as_int(v.z));
        ushort4v cr = *(const ushort4v*)(ci + __float_as_int(v.w));
        float f = v.x, g = 1.f - v.x, s = v.y;
        a0 = fmaf(s, w.x, a0);
        a1 = fmaf(s, w.y, a1);
        a2 = fmaf(s, w.z, a2);
        a3 = fmaf(s, w.w, a3);
        a0 = fmaf(g, bf16u_to_f(cl.x), a0);
        a1 = fmaf(g, bf16u_to_f(cl.y), a1);
        a2 = fmaf(g, bf16u_to_f(cl.z), a2);
        a3 = fmaf(g, bf16u_to_f(cl.w), a3);
        a0 = fmaf(f, bf16u_to_f(cr.x), a0);
        a1 = fmaf(f, bf16u_to_f(cr.y), a1);
        a2 = fmaf(f, bf16u_to_f(cr.z), a2);
        a3 = fmaf(f, bf16u_to_f(cr.w), a3);
    }
    float4 r; r.x = a0; r.y = a1; r.z = a2; r.w = a3;
    part4[(size_t)chunk * (Bb * Oo / 4) + (size_t)(b0 + bh) * (Oo / 4) + oq] = r;
}

// Kernel D: out[b][o] = bias[o] + sum_c partial[c][b][o]. 256 blocks.
__global__ __launch_bounds__(256) void kreduce(const float4* __restrict__ part4,
                                               const float4* __restrict__ bias4,
                                               float4* __restrict__ out4) {
    int gid = blockIdx.x * 256 + threadIdx.x;     // = b*64 + o4
    const float4* p = part4 + gid;
    float4 s = p[0];
#pragma unroll
    for (int c = 1; c < NCH; ++c) {
        float4 v = p[(size_t)c * (Bb * Oo / 4)];
        s.x += v.x; s.y += v.y; s.z += v.z; s.w += v.w;
    }
    float4 bv = bias4[gid & 63];
    s.x += bv.x; s.y += bv.y; s.z += bv.z; s.w += bv.w;
    out4[gid] = s;
}

extern "C" void kernel_launch(void* const* d_in, const int* in_sizes, int n_in,
                              void* d_out, int out_size, void* d_ws, size_t ws_size,
                              hipStream_t stream) {
    const float* x     = (const float*)d_in[0];
    const float* wbase = (const float*)d_in[1];
    const float* coeff = (const float*)d_in[2];
    const float* scale = (const float*)d_in[3];
    const float* bias  = (const float*)d_in[4];
    float* out = (float*)d_out;

    char* ws = (char*)d_ws;
    float4* fls = (float4*)ws;                                       // 4 MB
    size_t off = (size_t)Bb * Ii * sizeof(float4);
    u16* cp = (u16*)(ws + off);                                      // 16 MB
    off += (size_t)Ii * Kk * Oo * sizeof(u16);
    float* wt = (float*)(ws + off);                                  // 256 KB
    off += (size_t)Ii * Oo * sizeof(float);
    float4* part4 = (float4*)(ws + off);                             // 8 MB

    kprep<<<(Bb * Ii) / 256, 256, 0, stream>>>(x, wbase, fls, wt);
    kperm<<<Ii * 2, 256, 0, stream>>>(coeff, scale, cp);
    kmain<<<2048, 256, 0, stream>>>(fls, (const char*)cp, (const float4*)wt, part4);
    kreduce<<<(Bb * Oo / 4) / 256, 256, 0, stream>>>(part4, (const float4*)bias, (float4*)out);
}